// Round 2
// baseline (1850.645 us; speedup 1.0000x reference)
//
#include <hip/hip_runtime.h>

#define N_TOT  200000
#define NG_    100000
#define NU_    100000
#define E_CNT  3200000
#define C_CNT  1000000

// Packed fp32 atomic add: one fabric op per 2 floats (global_atomic_pk_add_f32,
// gfx90a+/gfx950). Falls back to 2 scalar unsafe atomics if builtin missing.
__device__ __forceinline__ void atomic_add2(float* p, float a, float b) {
#if __has_builtin(__builtin_amdgcn_global_atomic_fadd_v2f32)
    typedef float vf2 __attribute__((ext_vector_type(2)));
    vf2 v; v.x = a; v.y = b;
    __builtin_amdgcn_global_atomic_fadd_v2f32((vf2*)p, v);
#else
    unsafeAtomicAdd(p, a);
    unsafeAtomicAdd(p + 1, b);
#endif
}

// ---------------- Stage 1: edge scatter for conv1 (d=2) ----------------
__global__ __launch_bounds__(256) void scatter1(const int* __restrict__ src,
                                                const int* __restrict__ dst,
                                                const float* __restrict__ x,
                                                float* __restrict__ agg1) {
    int e = blockIdx.x * blockDim.x + threadIdx.x;
    if (e >= E_CNT) return;
    int s = src[e], d = dst[e];
    const float2 xv = *(const float2*)(x + 2 * s);
    atomic_add2(&agg1[2 * d], xv.x, xv.y);
}

// ---------------- Stage 2: node update conv1 (2 -> 8) ----------------
__global__ __launch_bounds__(256) void node1(const float* __restrict__ x,
                                             const float* __restrict__ agg1,
                                             const float* __restrict__ w_rel,
                                             const float* __restrict__ w_root,
                                             const float* __restrict__ b,
                                             float* __restrict__ h1) {
    int i = blockIdx.x * blockDim.x + threadIdx.x;
    if (i >= NG_) return;
    float a0 = agg1[2 * i], a1 = agg1[2 * i + 1];
    float x0 = x[2 * i],    x1 = x[2 * i + 1];
#pragma unroll
    for (int k = 0; k < 8; k++) {
        float v = a0 * w_rel[k] + a1 * w_rel[8 + k]
                + x0 * w_root[k] + x1 * w_root[8 + k] + b[k];
        h1[8 * i + k] = fmaxf(v, 0.f);
    }
}

// ---------------- Stage 3: edge scatter for conv2 (d=8) ----------------
__global__ __launch_bounds__(256) void scatter2(const int* __restrict__ src,
                                                const int* __restrict__ dst,
                                                const float* __restrict__ h1,
                                                float* __restrict__ agg2) {
    int e = blockIdx.x * blockDim.x + threadIdx.x;
    if (e >= E_CNT) return;
    int s = src[e], d = dst[e];
    const float4* hp = (const float4*)(h1 + 8 * s);
    float4 v0 = hp[0], v1 = hp[1];
    float* ap = agg2 + 8 * d;
    atomic_add2(ap + 0, v0.x, v0.y);
    atomic_add2(ap + 2, v0.z, v0.w);
    atomic_add2(ap + 4, v1.x, v1.y);
    atomic_add2(ap + 6, v1.z, v1.w);
}

// ---------------- Stage 4: node update conv2 (8 -> 16) ----------------
__global__ __launch_bounds__(256) void node2(const float* __restrict__ h1,
                                             const float* __restrict__ agg2,
                                             const float* __restrict__ w_rel,
                                             const float* __restrict__ w_root,
                                             const float* __restrict__ b,
                                             float* __restrict__ h2) {
    int i = blockIdx.x * blockDim.x + threadIdx.x;
    if (i >= NG_) return;
    float a[8], h[8];
    const float4* ap = (const float4*)(agg2 + 8 * i);
    const float4* hp = (const float4*)(h1 + 8 * i);
    float4 t;
    t = ap[0]; a[0]=t.x; a[1]=t.y; a[2]=t.z; a[3]=t.w;
    t = ap[1]; a[4]=t.x; a[5]=t.y; a[6]=t.z; a[7]=t.w;
    t = hp[0]; h[0]=t.x; h[1]=t.y; h[2]=t.z; h[3]=t.w;
    t = hp[1]; h[4]=t.x; h[5]=t.y; h[6]=t.z; h[7]=t.w;
#pragma unroll
    for (int k = 0; k < 16; k++) {
        float v = b[k];
#pragma unroll
        for (int j = 0; j < 8; j++)
            v += a[j] * w_rel[j * 16 + k] + h[j] * w_root[j * 16 + k];
        h2[16 * i + k] = fmaxf(v, 0.f);
    }
}

// ---------------- Stage 5: unconnected nodes (2 -> 16, no relu) ----------------
__global__ __launch_bounds__(256) void xu_kernel(const float* __restrict__ x,
                                                 const float* __restrict__ wu,
                                                 const float* __restrict__ bu,
                                                 float* __restrict__ xu) {
    int j = blockIdx.x * blockDim.x + threadIdx.x;
    if (j >= NU_) return;
    float x0 = x[2 * (NG_ + j)], x1 = x[2 * (NG_ + j) + 1];
#pragma unroll
    for (int k = 0; k < 16; k++)
        xu[16 * j + k] = x0 * wu[k] + x1 * wu[16 + k] + bu[k];
}

// ---------------- Stage 6: final MLP over candidates ----------------
__global__ __launch_bounds__(256) void final_mlp(const int* __restrict__ cand,
                                                 const float* __restrict__ h2,
                                                 const float* __restrict__ xu,
                                                 const float* __restrict__ wa,
                                                 const float* __restrict__ ba,
                                                 const float* __restrict__ wb,
                                                 const float* __restrict__ bb,
                                                 float* __restrict__ out) {
    __shared__ float s_waT[64 * 32];
    __shared__ float s_ba[64];
    __shared__ float s_wb[64];
    int t = threadIdx.x;
    for (int idx = t; idx < 2048; idx += blockDim.x) {
        int j = idx >> 5, i = idx & 31;
        s_waT[idx] = wa[i * 64 + j];
    }
    if (t < 64) { s_ba[t] = ba[t]; s_wb[t] = wb[t]; }
    __syncthreads();

    int c = blockIdx.x * blockDim.x + t;
    if (c >= C_CNT) return;
    int g = cand[2 * c], u = cand[2 * c + 1];

    float4 ec4[8];
    const float4* hp = (const float4*)(h2 + 16 * g);
    const float4* up = (const float4*)(xu + 16 * u);
    ec4[0] = hp[0]; ec4[1] = hp[1]; ec4[2] = hp[2]; ec4[3] = hp[3];
    ec4[4] = up[0]; ec4[5] = up[1]; ec4[6] = up[2]; ec4[7] = up[3];

    float acc = bb[0];
#pragma unroll 8
    for (int j = 0; j < 64; j++) {
        const float4* wp = (const float4*)&s_waT[j * 32];
        float v = s_ba[j];
#pragma unroll
        for (int q = 0; q < 8; q++) {
            float4 w = wp[q];
            float4 e = ec4[q];
            v += e.x * w.x + e.y * w.y + e.z * w.z + e.w * w.w;
        }
        acc += fmaxf(v, 0.f) * s_wb[j];
    }
    out[c] = acc;
}

extern "C" void kernel_launch(void* const* d_in, const int* in_sizes, int n_in,
                              void* d_out, int out_size, void* d_ws, size_t ws_size,
                              hipStream_t stream) {
    const float* x      = (const float*)d_in[0];
    const int*   cand   = (const int*)d_in[2];
    const int*   edges  = (const int*)d_in[3];   // [2, E]: src then dst
    const float* w1_rel = (const float*)d_in[4];
    const float* w1_root= (const float*)d_in[5];
    const float* b1     = (const float*)d_in[6];
    const float* w2_rel = (const float*)d_in[7];
    const float* w2_root= (const float*)d_in[8];
    const float* b2     = (const float*)d_in[9];
    const float* wu     = (const float*)d_in[10];
    const float* bu     = (const float*)d_in[11];
    const float* wa     = (const float*)d_in[12];
    const float* ba     = (const float*)d_in[13];
    const float* wb     = (const float*)d_in[14];
    const float* bb     = (const float*)d_in[15];
    float* out = (float*)d_out;

    const int* src = edges;
    const int* dst = edges + E_CNT;

    float* ws   = (float*)d_ws;
    float* agg1 = ws;                      // NG*2   = 200,000
    float* agg2 = ws + 200000;             // NG*8   = 800,000
    float* h1   = ws + 1000000;            // NG*8   = 800,000
    float* h2   = ws + 1800000;            // NG*16  = 1,600,000
    float* xu   = ws + 3400000;            // NU*16  = 1,600,000

    hipMemsetAsync(agg1, 0, 1000000 * sizeof(float), stream);

    dim3 blk(256);
    dim3 grE((E_CNT + 255) / 256);
    dim3 grN((NG_ + 255) / 256);
    dim3 grU((NU_ + 255) / 256);
    dim3 grC((C_CNT + 255) / 256);

    scatter1<<<grE, blk, 0, stream>>>(src, dst, x, agg1);
    node1<<<grN, blk, 0, stream>>>(x, agg1, w1_rel, w1_root, b1, h1);
    scatter2<<<grE, blk, 0, stream>>>(src, dst, h1, agg2);
    node2<<<grN, blk, 0, stream>>>(h1, agg2, w2_rel, w2_root, b2, h2);
    xu_kernel<<<grU, blk, 0, stream>>>(x, wu, bu, xu);
    final_mlp<<<grC, blk, 0, stream>>>(cand, h2, xu, wa, ba, wb, bb, out);
}

// Round 3
// 628.298 us; speedup vs baseline: 2.9455x; 2.9455x over previous
//
#include <hip/hip_runtime.h>

#define N_TOT  200000
#define NG_    100000
#define NU_    100000
#define E_CNT  3200000
#define C_CNT  1000000

#define NB_SCAN 391              // ceil(NG_/256)

// ======================= CSR-gather path =======================

// ---- hist: cnt[d]++ over all edges (1 int atomic per edge) ----
__global__ __launch_bounds__(256) void hist_kernel(const int* __restrict__ dst,
                                                   int* __restrict__ cnt) {
    int e = blockIdx.x * blockDim.x + threadIdx.x;
    if (e >= E_CNT) return;
    atomicAdd(&cnt[dst[e]], 1);
}

// ---- scan part 1: per-block sums of cnt ----
__global__ __launch_bounds__(256) void scan_part(const int* __restrict__ cnt,
                                                 int* __restrict__ bsum) {
    __shared__ int s[256];
    int t = threadIdx.x;
    int i = blockIdx.x * 256 + t;
    s[t] = (i < NG_) ? cnt[i] : 0;
    __syncthreads();
#pragma unroll
    for (int off = 128; off > 0; off >>= 1) {
        if (t < off) s[t] += s[t + off];
        __syncthreads();
    }
    if (t == 0) bsum[blockIdx.x] = s[0];
}

// ---- scan part 2: exclusive scan of block sums (single block, 512 thr) ----
__global__ __launch_bounds__(512) void scan_bsums(const int* __restrict__ bsum,
                                                  int* __restrict__ boff) {
    __shared__ int s[512];
    int t = threadIdx.x;
    s[t] = (t < NB_SCAN) ? bsum[t] : 0;
    __syncthreads();
    for (int off = 1; off < 512; off <<= 1) {
        int v = (t >= off) ? s[t - off] : 0;
        __syncthreads();
        s[t] += v;
        __syncthreads();
    }
    if (t < NB_SCAN) boff[t] = (t == 0) ? 0 : s[t - 1];
}

// ---- scan part 3: block-local scan + block offset -> row[] ----
__global__ __launch_bounds__(256) void scan_final(const int* __restrict__ cnt,
                                                  const int* __restrict__ boff,
                                                  int* __restrict__ row) {
    __shared__ int s[256];
    int t = threadIdx.x;
    int i = blockIdx.x * 256 + t;
    int v = (i < NG_) ? cnt[i] : 0;
    s[t] = v;
    __syncthreads();
    for (int off = 1; off < 256; off <<= 1) {
        int u = (t >= off) ? s[t - off] : 0;
        __syncthreads();
        s[t] += u;
        __syncthreads();
    }
    if (i < NG_) {
        row[i] = boff[blockIdx.x] + s[t] - v;          // exclusive
        if (i == NG_ - 1) row[NG_] = boff[blockIdx.x] + s[t];
    }
}

// ---- permute: perm[row[d] + cur[d]++] = src  (1 int atomic per edge) ----
__global__ __launch_bounds__(256) void permute_kernel(const int* __restrict__ src,
                                                      const int* __restrict__ dst,
                                                      const int* __restrict__ row,
                                                      int* __restrict__ cur,
                                                      int* __restrict__ perm) {
    int e = blockIdx.x * blockDim.x + threadIdx.x;
    if (e >= E_CNT) return;
    int d = dst[e];
    int pos = row[d] + atomicAdd(&cur[d], 1);
    perm[pos] = src[e];
}

// ---- conv1 fused: gather-sum x over in-edges + (2->8) GEMV + relu ----
__global__ __launch_bounds__(256) void conv1_kernel(const int* __restrict__ row,
                                                    const int* __restrict__ perm,
                                                    const float* __restrict__ x,
                                                    const float* __restrict__ w_rel,
                                                    const float* __restrict__ w_root,
                                                    const float* __restrict__ b,
                                                    float* __restrict__ h1) {
    int i = blockIdx.x * blockDim.x + threadIdx.x;
    if (i >= NG_) return;
    int beg = row[i], end = row[i + 1];
    float a0 = 0.f, a1 = 0.f;
    for (int j = beg; j < end; j++) {
        int s = perm[j];
        float2 v = *(const float2*)(x + 2 * s);
        a0 += v.x; a1 += v.y;
    }
    float2 xi = *(const float2*)(x + 2 * i);
#pragma unroll
    for (int k = 0; k < 8; k++) {
        float v = a0 * w_rel[k] + a1 * w_rel[8 + k]
                + xi.x * w_root[k] + xi.y * w_root[8 + k] + b[k];
        h1[8 * i + k] = fmaxf(v, 0.f);
    }
}

// ---- conv2 fused: gather-sum h1 over in-edges + (8->16) GEMV + relu ----
__global__ __launch_bounds__(256) void conv2_kernel(const int* __restrict__ row,
                                                    const int* __restrict__ perm,
                                                    const float* __restrict__ h1,
                                                    const float* __restrict__ w_rel,
                                                    const float* __restrict__ w_root,
                                                    const float* __restrict__ b,
                                                    float* __restrict__ h2) {
    int i = blockIdx.x * blockDim.x + threadIdx.x;
    if (i >= NG_) return;
    int beg = row[i], end = row[i + 1];
    float a[8] = {0.f, 0.f, 0.f, 0.f, 0.f, 0.f, 0.f, 0.f};
    for (int j = beg; j < end; j++) {
        int s = perm[j];
        const float4* hp = (const float4*)(h1 + 8 * s);
        float4 v0 = hp[0], v1 = hp[1];
        a[0] += v0.x; a[1] += v0.y; a[2] += v0.z; a[3] += v0.w;
        a[4] += v1.x; a[5] += v1.y; a[6] += v1.z; a[7] += v1.w;
    }
    float h[8];
    const float4* hp = (const float4*)(h1 + 8 * i);
    float4 t0 = hp[0], t1 = hp[1];
    h[0]=t0.x; h[1]=t0.y; h[2]=t0.z; h[3]=t0.w;
    h[4]=t1.x; h[5]=t1.y; h[6]=t1.z; h[7]=t1.w;
#pragma unroll
    for (int k = 0; k < 16; k++) {
        float v = b[k];
#pragma unroll
        for (int j = 0; j < 8; j++)
            v += a[j] * w_rel[j * 16 + k] + h[j] * w_root[j * 16 + k];
        h2[16 * i + k] = fmaxf(v, 0.f);
    }
}

// ---- final MLP, xu projection fused in ----
__global__ __launch_bounds__(256) void final_mlp(const int* __restrict__ cand,
                                                 const float* __restrict__ h2,
                                                 const float* __restrict__ x,
                                                 const float* __restrict__ wu,
                                                 const float* __restrict__ bu,
                                                 const float* __restrict__ wa,
                                                 const float* __restrict__ ba,
                                                 const float* __restrict__ wb,
                                                 const float* __restrict__ bb,
                                                 float* __restrict__ out) {
    __shared__ float s_waT[64 * 32];   // s_waT[j][i] = wa[i*64 + j]
    __shared__ float s_ba[64];
    __shared__ float s_wb[64];
    __shared__ float s_wu[32];
    __shared__ float s_bu[16];
    int t = threadIdx.x;
    for (int idx = t; idx < 2048; idx += blockDim.x) {
        int j = idx >> 5, i = idx & 31;
        s_waT[idx] = wa[i * 64 + j];
    }
    if (t < 64) { s_ba[t] = ba[t]; s_wb[t] = wb[t]; }
    if (t < 32) s_wu[t] = wu[t];
    if (t < 16) s_bu[t] = bu[t];
    __syncthreads();

    int c = blockIdx.x * blockDim.x + t;
    if (c >= C_CNT) return;
    int g = cand[2 * c], u = cand[2 * c + 1];

    float ec[32];
    const float4* hp = (const float4*)(h2 + 16 * g);
#pragma unroll
    for (int q = 0; q < 4; q++) {
        float4 v = hp[q];
        ec[4*q] = v.x; ec[4*q+1] = v.y; ec[4*q+2] = v.z; ec[4*q+3] = v.w;
    }
    float2 xv = *(const float2*)(x + 2 * (NG_ + u));
#pragma unroll
    for (int k = 0; k < 16; k++)
        ec[16 + k] = xv.x * s_wu[k] + xv.y * s_wu[16 + k] + s_bu[k];

    float acc = bb[0];
#pragma unroll 8
    for (int j = 0; j < 64; j++) {
        const float4* wp = (const float4*)&s_waT[j * 32];
        float v = s_ba[j];
#pragma unroll
        for (int q = 0; q < 8; q++) {
            float4 w = wp[q];
            v += ec[4*q] * w.x + ec[4*q+1] * w.y + ec[4*q+2] * w.z + ec[4*q+3] * w.w;
        }
        acc += fmaxf(v, 0.f) * s_wb[j];
    }
    out[c] = acc;
}

// ======================= fallback atomic path (small ws) =======================

__global__ __launch_bounds__(256) void fb_scatter1(const int* __restrict__ src,
                                                   const int* __restrict__ dst,
                                                   const float* __restrict__ x,
                                                   float* __restrict__ agg1) {
    int e = blockIdx.x * blockDim.x + threadIdx.x;
    if (e >= E_CNT) return;
    int s = src[e], d = dst[e];
    unsafeAtomicAdd(&agg1[2 * d],     x[2 * s]);
    unsafeAtomicAdd(&agg1[2 * d + 1], x[2 * s + 1]);
}

__global__ __launch_bounds__(256) void fb_scatter2(const int* __restrict__ src,
                                                   const int* __restrict__ dst,
                                                   const float* __restrict__ h1,
                                                   float* __restrict__ agg2) {
    int e = blockIdx.x * blockDim.x + threadIdx.x;
    if (e >= E_CNT) return;
    int s = src[e], d = dst[e];
    const float4* hp = (const float4*)(h1 + 8 * s);
    float4 v0 = hp[0], v1 = hp[1];
    float* ap = agg2 + 8 * d;
    unsafeAtomicAdd(ap + 0, v0.x); unsafeAtomicAdd(ap + 1, v0.y);
    unsafeAtomicAdd(ap + 2, v0.z); unsafeAtomicAdd(ap + 3, v0.w);
    unsafeAtomicAdd(ap + 4, v1.x); unsafeAtomicAdd(ap + 5, v1.y);
    unsafeAtomicAdd(ap + 6, v1.z); unsafeAtomicAdd(ap + 7, v1.w);
}

__global__ __launch_bounds__(256) void fb_node1(const float* __restrict__ x,
                                                const float* __restrict__ agg1,
                                                const float* __restrict__ w_rel,
                                                const float* __restrict__ w_root,
                                                const float* __restrict__ b,
                                                float* __restrict__ h1) {
    int i = blockIdx.x * blockDim.x + threadIdx.x;
    if (i >= NG_) return;
    float a0 = agg1[2 * i], a1 = agg1[2 * i + 1];
    float x0 = x[2 * i],    x1 = x[2 * i + 1];
#pragma unroll
    for (int k = 0; k < 8; k++) {
        float v = a0 * w_rel[k] + a1 * w_rel[8 + k]
                + x0 * w_root[k] + x1 * w_root[8 + k] + b[k];
        h1[8 * i + k] = fmaxf(v, 0.f);
    }
}

__global__ __launch_bounds__(256) void fb_node2(const float* __restrict__ h1,
                                                const float* __restrict__ agg2,
                                                const float* __restrict__ w_rel,
                                                const float* __restrict__ w_root,
                                                const float* __restrict__ b,
                                                float* __restrict__ h2) {
    int i = blockIdx.x * blockDim.x + threadIdx.x;
    if (i >= NG_) return;
    float a[8], h[8];
    const float4* ap = (const float4*)(agg2 + 8 * i);
    const float4* hp = (const float4*)(h1 + 8 * i);
    float4 t;
    t = ap[0]; a[0]=t.x; a[1]=t.y; a[2]=t.z; a[3]=t.w;
    t = ap[1]; a[4]=t.x; a[5]=t.y; a[6]=t.z; a[7]=t.w;
    t = hp[0]; h[0]=t.x; h[1]=t.y; h[2]=t.z; h[3]=t.w;
    t = hp[1]; h[4]=t.x; h[5]=t.y; h[6]=t.z; h[7]=t.w;
#pragma unroll
    for (int k = 0; k < 16; k++) {
        float v = b[k];
#pragma unroll
        for (int j = 0; j < 8; j++)
            v += a[j] * w_rel[j * 16 + k] + h[j] * w_root[j * 16 + k];
        h2[16 * i + k] = fmaxf(v, 0.f);
    }
}

// ======================= launch =======================

extern "C" void kernel_launch(void* const* d_in, const int* in_sizes, int n_in,
                              void* d_out, int out_size, void* d_ws, size_t ws_size,
                              hipStream_t stream) {
    const float* x      = (const float*)d_in[0];
    const int*   cand   = (const int*)d_in[2];
    const int*   edges  = (const int*)d_in[3];   // [2, E]: src then dst
    const float* w1_rel = (const float*)d_in[4];
    const float* w1_root= (const float*)d_in[5];
    const float* b1     = (const float*)d_in[6];
    const float* w2_rel = (const float*)d_in[7];
    const float* w2_root= (const float*)d_in[8];
    const float* b2     = (const float*)d_in[9];
    const float* wu     = (const float*)d_in[10];
    const float* bu     = (const float*)d_in[11];
    const float* wa     = (const float*)d_in[12];
    const float* ba     = (const float*)d_in[13];
    const float* wb     = (const float*)d_in[14];
    const float* bb     = (const float*)d_in[15];
    float* out = (float*)d_out;

    const int* src = edges;
    const int* dst = edges + E_CNT;

    dim3 blk(256);
    dim3 grE((E_CNT + 255) / 256);
    dim3 grN((NG_ + 255) / 256);
    dim3 grC((C_CNT + 255) / 256);

    // CSR-path workspace (ints unless noted):
    //   cnt   [0      .. 100,000)   zeroed
    //   cur   [100,000.. 200,000)   zeroed
    //   row   [200,000.. 300,001)
    //   bsum  [300,016.. 300,528)
    //   boff  [300,528.. 301,040)
    //   perm  [301,040.. 3,501,040)
    //   h1  f [3,501,040.. 4,301,040)
    //   h2  f [4,301,040.. 5,901,040)
    const size_t CSR_NEED = 5901040ull * 4ull;

    int* ws_i = (int*)d_ws;
    if (ws_size >= CSR_NEED) {
        int*   cnt  = ws_i;
        int*   cur  = ws_i + 100000;
        int*   row  = ws_i + 200000;
        int*   bsum = ws_i + 300016;
        int*   boff = ws_i + 300528;
        int*   perm = ws_i + 301040;
        float* h1   = (float*)(ws_i + 3501040);
        float* h2   = (float*)(ws_i + 4301040);

        hipMemsetAsync(cnt, 0, 200000 * sizeof(int), stream);  // cnt + cur

        hist_kernel<<<grE, blk, 0, stream>>>(dst, cnt);
        scan_part <<<NB_SCAN, blk, 0, stream>>>(cnt, bsum);
        scan_bsums<<<1, 512, 0, stream>>>(bsum, boff);
        scan_final<<<NB_SCAN, blk, 0, stream>>>(cnt, boff, row);
        permute_kernel<<<grE, blk, 0, stream>>>(src, dst, row, cur, perm);
        conv1_kernel<<<grN, blk, 0, stream>>>(row, perm, x, w1_rel, w1_root, b1, h1);
        conv2_kernel<<<grN, blk, 0, stream>>>(row, perm, h1, w2_rel, w2_root, b2, h2);
        final_mlp<<<grC, blk, 0, stream>>>(cand, h2, x, wu, bu, wa, ba, wb, bb, out);
    } else {
        // fallback: atomic scatter path (20 MB)
        float* ws   = (float*)d_ws;
        float* agg1 = ws;                      // 200,000
        float* agg2 = ws + 200000;             // 800,000
        float* h1   = ws + 1000000;            // 800,000
        float* h2   = ws + 1800000;            // 1,600,000

        hipMemsetAsync(agg1, 0, 1000000 * sizeof(float), stream);
        fb_scatter1<<<grE, blk, 0, stream>>>(src, dst, x, agg1);
        fb_node1<<<grN, blk, 0, stream>>>(x, agg1, w1_rel, w1_root, b1, h1);
        fb_scatter2<<<grE, blk, 0, stream>>>(src, dst, h1, agg2);
        fb_node2<<<grN, blk, 0, stream>>>(h1, agg2, w2_rel, w2_root, b2, h2);
        final_mlp<<<grC, blk, 0, stream>>>(cand, h2, x, wu, bu, wa, ba, wb, bb, out);
    }
}

// Round 4
// 458.615 us; speedup vs baseline: 4.0353x; 1.3700x over previous
//
#include <hip/hip_runtime.h>

#define N_TOT  200000
#define NG_    100000
#define NU_    100000
#define E_CNT  3200000
#define C_CNT  1000000

#define NBUCK  196        // ceil(NG_/512): bucket k covers nodes [k*512, k*512+512)
#define NBLK   256        // edge chunks
#define CHUNK  12500      // E_CNT / NBLK exactly

// ---- Phase A: per-(chunk,bucket) histogram, LDS-only atomics ----
__global__ __launch_bounds__(256) void phaseA(const int* __restrict__ dst,
                                              int* __restrict__ cnt_mat) {
    __shared__ int hcnt[NBUCK];
    int t = threadIdx.x;
    if (t < NBUCK) hcnt[t] = 0;
    __syncthreads();
    int beg = blockIdx.x * CHUNK, end = beg + CHUNK;
    for (int e = beg + t; e < end; e += 256)
        atomicAdd(&hcnt[dst[e] >> 9], 1);
    __syncthreads();
    if (t < NBUCK) cnt_mat[blockIdx.x * NBUCK + t] = hcnt[t];
}

// ---- Phase B1: per-column (bucket) exclusive scan over chunks ----
__global__ __launch_bounds__(256) void phaseB1(const int* __restrict__ cnt_mat,
                                               int* __restrict__ off_mat,
                                               int* __restrict__ colsum) {
    __shared__ int s[256];
    int t = threadIdx.x;          // chunk index
    int k = blockIdx.x;           // bucket index
    int v = cnt_mat[t * NBUCK + k];
    s[t] = v;
    __syncthreads();
    for (int off = 1; off < 256; off <<= 1) {
        int u = (t >= off) ? s[t - off] : 0;
        __syncthreads();
        s[t] += u;
        __syncthreads();
    }
    off_mat[t * NBUCK + k] = s[t] - v;     // exclusive within column
    if (t == 255) colsum[k] = s[255];
}

// ---- Phase B2: exclusive scan of bucket totals -> bbase[0..NBUCK] ----
__global__ __launch_bounds__(256) void phaseB2(const int* __restrict__ colsum,
                                               int* __restrict__ bbase) {
    __shared__ int s[256];
    int t = threadIdx.x;
    int v = (t < NBUCK) ? colsum[t] : 0;
    s[t] = v;
    __syncthreads();
    for (int off = 1; off < 256; off <<= 1) {
        int u = (t >= off) ? s[t - off] : 0;
        __syncthreads();
        s[t] += u;
        __syncthreads();
    }
    if (t < NBUCK) bbase[t] = s[t] - v;
    if (t == NBUCK - 1) bbase[NBUCK] = s[t];
}

// ---- Phase C: bucket-scatter packed (src<<9 | bin); LDS-only atomics ----
__global__ __launch_bounds__(256) void phaseC(const int* __restrict__ src,
                                              const int* __restrict__ dst,
                                              const int* __restrict__ off_mat,
                                              const int* __restrict__ bbase,
                                              int* __restrict__ pairs) {
    __shared__ int loc[NBUCK];
    int t = threadIdx.x;
    if (t < NBUCK) loc[t] = bbase[t] + off_mat[blockIdx.x * NBUCK + t];
    __syncthreads();
    int beg = blockIdx.x * CHUNK, end = beg + CHUNK;
    for (int e = beg + t; e < end; e += 256) {
        int d = dst[e], s = src[e];
        int k = d >> 9;
        int pos = atomicAdd(&loc[k], 1);
        pairs[pos] = (s << 9) | (d & 511);
    }
}

// ---- conv1: per-bucket LDS aggregation (stride 3 pad) + 2->8 GEMV + relu ----
__global__ __launch_bounds__(1024) void conv1_kernel(const int* __restrict__ bbase,
                                                     const int* __restrict__ pairs,
                                                     const float* __restrict__ x,
                                                     const float* __restrict__ w_rel,
                                                     const float* __restrict__ w_root,
                                                     const float* __restrict__ b,
                                                     float* __restrict__ h1) {
    __shared__ float acc[512 * 3];
    int t = threadIdx.x, k = blockIdx.x;
    if (t < 512) { acc[3*t] = 0.f; acc[3*t+1] = 0.f; acc[3*t+2] = 0.f; }
    __syncthreads();
    int beg = bbase[k], end = bbase[k + 1];
    for (int e = beg + t; e < end; e += 1024) {
        int p = pairs[e];
        int s = p >> 9, bin = p & 511;
        float2 xv = *(const float2*)(x + 2 * s);
        atomicAdd(&acc[3 * bin],     xv.x);
        atomicAdd(&acc[3 * bin + 1], xv.y);
    }
    __syncthreads();
    if (t < 512) {
        int i = (k << 9) + t;
        if (i < NG_) {
            float a0 = acc[3*t], a1 = acc[3*t+1];
            float2 xi = *(const float2*)(x + 2 * i);
#pragma unroll
            for (int j = 0; j < 8; j++) {
                float v = a0 * w_rel[j] + a1 * w_rel[8 + j]
                        + xi.x * w_root[j] + xi.y * w_root[8 + j] + b[j];
                h1[8 * i + j] = fmaxf(v, 0.f);
            }
        }
    }
}

// ---- conv2: per-bucket LDS aggregation (stride 9 pad) + 8->16 GEMV + relu ----
__global__ __launch_bounds__(1024) void conv2_kernel(const int* __restrict__ bbase,
                                                     const int* __restrict__ pairs,
                                                     const float* __restrict__ h1,
                                                     const float* __restrict__ w_rel,
                                                     const float* __restrict__ w_root,
                                                     const float* __restrict__ b,
                                                     float* __restrict__ h2) {
    __shared__ float acc[512 * 9];   // 18 KB, stride 9 (coprime 32) -> conflict-free
    int t = threadIdx.x, k = blockIdx.x;
    for (int i = t; i < 512 * 9; i += 1024) acc[i] = 0.f;
    __syncthreads();
    int beg = bbase[k], end = bbase[k + 1];
    for (int e = beg + t; e < end; e += 1024) {
        int p = pairs[e];
        int s = p >> 9, bin = p & 511;
        const float4* hp = (const float4*)(h1 + 8 * s);
        float4 v0 = hp[0], v1 = hp[1];
        float* ap = &acc[9 * bin];
        atomicAdd(ap + 0, v0.x); atomicAdd(ap + 1, v0.y);
        atomicAdd(ap + 2, v0.z); atomicAdd(ap + 3, v0.w);
        atomicAdd(ap + 4, v1.x); atomicAdd(ap + 5, v1.y);
        atomicAdd(ap + 6, v1.z); atomicAdd(ap + 7, v1.w);
    }
    __syncthreads();
    if (t < 512) {
        int i = (k << 9) + t;
        if (i < NG_) {
            float a[8], h[8];
#pragma unroll
            for (int j = 0; j < 8; j++) a[j] = acc[9 * t + j];
            const float4* hp = (const float4*)(h1 + 8 * i);
            float4 t0 = hp[0], t1 = hp[1];
            h[0]=t0.x; h[1]=t0.y; h[2]=t0.z; h[3]=t0.w;
            h[4]=t1.x; h[5]=t1.y; h[6]=t1.z; h[7]=t1.w;
#pragma unroll
            for (int kk = 0; kk < 16; kk++) {
                float v = b[kk];
#pragma unroll
                for (int j = 0; j < 8; j++)
                    v += a[j] * w_rel[j * 16 + kk] + h[j] * w_root[j * 16 + kk];
                h2[16 * i + kk] = fmaxf(v, 0.f);
            }
        }
    }
}

// ---- final MLP, xu projection fused in ----
__global__ __launch_bounds__(256) void final_mlp(const int* __restrict__ cand,
                                                 const float* __restrict__ h2,
                                                 const float* __restrict__ x,
                                                 const float* __restrict__ wu,
                                                 const float* __restrict__ bu,
                                                 const float* __restrict__ wa,
                                                 const float* __restrict__ ba,
                                                 const float* __restrict__ wb,
                                                 const float* __restrict__ bb,
                                                 float* __restrict__ out) {
    __shared__ float s_waT[64 * 32];   // s_waT[j][i] = wa[i*64 + j]
    __shared__ float s_ba[64];
    __shared__ float s_wb[64];
    __shared__ float s_wu[32];
    __shared__ float s_bu[16];
    int t = threadIdx.x;
    for (int idx = t; idx < 2048; idx += blockDim.x) {
        int j = idx >> 5, i = idx & 31;
        s_waT[idx] = wa[i * 64 + j];
    }
    if (t < 64) { s_ba[t] = ba[t]; s_wb[t] = wb[t]; }
    if (t < 32) s_wu[t] = wu[t];
    if (t < 16) s_bu[t] = bu[t];
    __syncthreads();

    int c = blockIdx.x * blockDim.x + t;
    if (c >= C_CNT) return;
    int g = cand[2 * c], u = cand[2 * c + 1];

    float ec[32];
    const float4* hp = (const float4*)(h2 + 16 * g);
#pragma unroll
    for (int q = 0; q < 4; q++) {
        float4 v = hp[q];
        ec[4*q] = v.x; ec[4*q+1] = v.y; ec[4*q+2] = v.z; ec[4*q+3] = v.w;
    }
    float2 xv = *(const float2*)(x + 2 * (NG_ + u));
#pragma unroll
    for (int k = 0; k < 16; k++)
        ec[16 + k] = xv.x * s_wu[k] + xv.y * s_wu[16 + k] + s_bu[k];

    float acc = bb[0];
#pragma unroll 8
    for (int j = 0; j < 64; j++) {
        const float4* wp = (const float4*)&s_waT[j * 32];
        float v = s_ba[j];
#pragma unroll
        for (int q = 0; q < 8; q++) {
            float4 w = wp[q];
            v += ec[4*q] * w.x + ec[4*q+1] * w.y + ec[4*q+2] * w.z + ec[4*q+3] * w.w;
        }
        acc += fmaxf(v, 0.f) * s_wb[j];
    }
    out[c] = acc;
}

// ======================= launch =======================

extern "C" void kernel_launch(void* const* d_in, const int* in_sizes, int n_in,
                              void* d_out, int out_size, void* d_ws, size_t ws_size,
                              hipStream_t stream) {
    const float* x      = (const float*)d_in[0];
    const int*   cand   = (const int*)d_in[2];
    const int*   edges  = (const int*)d_in[3];   // [2, E]: src then dst
    const float* w1_rel = (const float*)d_in[4];
    const float* w1_root= (const float*)d_in[5];
    const float* b1     = (const float*)d_in[6];
    const float* w2_rel = (const float*)d_in[7];
    const float* w2_root= (const float*)d_in[8];
    const float* b2     = (const float*)d_in[9];
    const float* wu     = (const float*)d_in[10];
    const float* bu     = (const float*)d_in[11];
    const float* wa     = (const float*)d_in[12];
    const float* ba     = (const float*)d_in[13];
    const float* wb     = (const float*)d_in[14];
    const float* bb     = (const float*)d_in[15];
    float* out = (float*)d_out;

    const int* src = edges;
    const int* dst = edges + E_CNT;

    // ws layout (int units):
    //   cnt_mat [0        .. 50,176)
    //   off_mat [50,176   .. 100,352)
    //   colsum  [100,352  .. 100,548)
    //   bbase   [100,608  .. 100,805)
    //   pairs   [100,864  .. 3,300,864)
    //   h1 (f)  [3,300,864 .. 4,100,864)
    //   h2 (f)  [4,100,864 .. 5,700,864)   -> 22.8 MB total
    int* ws_i = (int*)d_ws;
    int*   cnt_mat = ws_i;
    int*   off_mat = ws_i + 50176;
    int*   colsum  = ws_i + 100352;
    int*   bbase   = ws_i + 100608;
    int*   pairs   = ws_i + 100864;
    float* h1      = (float*)(ws_i + 3300864);
    float* h2      = (float*)(ws_i + 4100864);

    dim3 blk256(256);

    phaseA <<<NBLK, blk256, 0, stream>>>(dst, cnt_mat);
    phaseB1<<<NBUCK, blk256, 0, stream>>>(cnt_mat, off_mat, colsum);
    phaseB2<<<1, blk256, 0, stream>>>(colsum, bbase);
    phaseC <<<NBLK, blk256, 0, stream>>>(src, dst, off_mat, bbase, pairs);
    conv1_kernel<<<NBUCK, 1024, 0, stream>>>(bbase, pairs, x, w1_rel, w1_root, b1, h1);
    conv2_kernel<<<NBUCK, 1024, 0, stream>>>(bbase, pairs, h1, w2_rel, w2_root, b2, h2);
    final_mlp<<<(C_CNT + 255) / 256, blk256, 0, stream>>>(cand, h2, x, wu, bu, wa, ba, wb, bb, out);
}